// Round 2
// baseline (928.831 us; speedup 1.0000x reference)
//
#include <hip/hip_runtime.h>

#define B_TOT   20000
#define M_TOT   49
#define IN_DIM  128
#define OUT_DIM 128
#define TILE_B  32
#define NT      5      // b-tiles per block
#define BX      125    // BX * NT * TILE_B == B_TOT exactly

typedef short  v8s __attribute__((ext_vector_type(8)));
typedef float  v4f __attribute__((ext_vector_type(4)));

__device__ __forceinline__ short f2bf(float x) {
    union { float f; unsigned int u; } c; c.f = x;
    unsigned int r = c.u + 0x7FFFu + ((c.u >> 16) & 1u);   // RNE
    return (short)(r >> 16);
}

typedef __attribute__((address_space(1))) void* gas_ptr;
typedef __attribute__((address_space(3))) void* las_ptr;

// async global->LDS DMA, 16B per lane (fire-and-forget, counted by vmcnt)
__device__ __forceinline__ void dma16(const void* g, void* s) {
    __builtin_amdgcn_global_load_lds((gas_ptr)g, (las_ptr)s, 16, 0, 0);
}

// One block: one m, NT consecutive 32-row b-tiles. 256 threads = 4 waves.
// A: fp32 in LDS via global_load_lds, double-buffered, source pre-swizzled
//    (chunk ^= row&7) so stride-128 ds_read_b128 is 2-way (free).
// W[l]: loaded once per block, held as bf16 fragments in registers (64 VGPR).
// Wave (wr,wc): 16 rows x 64 cols of each 32x128 tile.
// Raw s_barrier + counted vmcnt: DMA for tile t+1 stays in flight across
// the barrier while tile t computes (never vmcnt(0) in the loop).
__global__ __launch_bounds__(256, 4)
void so3_linear_kernel(const float* __restrict__ inp,
                       const float* __restrict__ wgt,
                       const float* __restrict__ bias,
                       float* __restrict__ out) {
    __shared__ __align__(16) float As[2][TILE_B][IN_DIM];   // 2 x 16 KiB

    const int tid = threadIdx.x;
    const int m   = blockIdx.y;
    int l = 0;
    while ((l + 1) * (l + 1) <= m) ++l;   // l = floor(sqrt(m))

    const int lane = tid & 63;
    const int lr   = lane & 15;
    const int quad = lane >> 4;
    const int wave = tid >> 6;
    const int wr   = wave & 1;            // row half (16 rows)
    const int wc   = wave >> 1;           // col half (64 cols)

    const int b_blk0 = blockIdx.x * (NT * TILE_B);

    // ---- issue DMA for tile 0 FIRST (HBM latency hides under W load) ----
    #pragma unroll
    for (int it = 0; it < 4; ++it) {
        int C  = it * 256 + tid;          // 16B chunk index within tile
        int r  = C >> 5;                  // tile row 0..31
        int cs = C & 31;                  // swizzled chunk slot in row
        int c  = cs ^ (r & 7);            // global chunk that lands here
        const float* src = inp + ((size_t)(b_blk0 + r) * M_TOT + m) * IN_DIM + c * 4;
        dma16(src, &As[0][0][0] + C * 4);
    }

    // ---- W fragments resident in registers (bf16), once per block ----
    v8s bw[4][4];   // [kk][j]
    {
        const float* wb = wgt + (size_t)l * OUT_DIM * IN_DIM
                        + (size_t)(wc * 64 + lr) * IN_DIM + quad * 8;
        #pragma unroll
        for (int j = 0; j < 4; ++j) {
            #pragma unroll
            for (int kk = 0; kk < 4; ++kk) {
                const float* p = wb + j * 16 * IN_DIM + kk * 32;
                float4 w0 = *(const float4*)(p);
                float4 w1 = *(const float4*)(p + 4);
                v8s f;
                f[0] = f2bf(w0.x); f[1] = f2bf(w0.y);
                f[2] = f2bf(w0.z); f[3] = f2bf(w0.w);
                f[4] = f2bf(w1.x); f[5] = f2bf(w1.y);
                f[6] = f2bf(w1.z); f[7] = f2bf(w1.w);
                bw[kk][j] = f;
            }
        }
    }

    const int arow = wr * 16 + lr;        // LDS row this lane reads
    const int sw   = arow & 7;            // read-side un-swizzle

    #pragma unroll
    for (int t = 0; t < NT; ++t) {
        const int cur = t & 1;

        // issue DMA for tile t+1 into the other buffer
        if (t + 1 < NT) {
            const int tb = b_blk0 + (t + 1) * TILE_B;
            #pragma unroll
            for (int it = 0; it < 4; ++it) {
                int C  = it * 256 + tid;
                int r  = C >> 5;
                int cs = C & 31;
                int c  = cs ^ (r & 7);
                const float* src = inp + ((size_t)(tb + r) * M_TOT + m) * IN_DIM + c * 4;
                dma16(src, &As[cur ^ 1][0][0] + C * 4);
            }
        }

        // drain THIS tile's DMA only; keep next tile's (4) + prev stores (4) in flight
        if (t == 0 || t == NT - 1)
            asm volatile("s_waitcnt vmcnt(4)" ::: "memory");
        else
            asm volatile("s_waitcnt vmcnt(8)" ::: "memory");
        asm volatile("s_barrier" ::: "memory");   // raw: no implicit vmcnt(0) drain

        v4f acc[4];
        #pragma unroll
        for (int j = 0; j < 4; ++j) acc[j] = (v4f)(0.f);

        #pragma unroll
        for (int kk = 0; kk < 4; ++kk) {
            const int c0 = (kk * 8 + quad * 2)     ^ sw;
            const int c1 = (kk * 8 + quad * 2 + 1) ^ sw;
            v4f a0 = *(const v4f*)&As[cur][arow][c0 * 4];
            v4f a1 = *(const v4f*)&As[cur][arow][c1 * 4];
            v8s af;
            af[0] = f2bf(a0[0]); af[1] = f2bf(a0[1]);
            af[2] = f2bf(a0[2]); af[3] = f2bf(a0[3]);
            af[4] = f2bf(a1[0]); af[5] = f2bf(a1[1]);
            af[6] = f2bf(a1[2]); af[7] = f2bf(a1[3]);
            #pragma unroll
            for (int j = 0; j < 4; ++j)
                acc[j] = __builtin_amdgcn_mfma_f32_16x16x32_bf16(
                             bw[kk][j], af, acc[j], 0, 0, 0);
        }

        // all LDS reads of buf[cur] done -> next iter may DMA into it
        asm volatile("s_barrier" ::: "memory");

        // epilogue overlaps next iteration's DMA/wait
        const int gb = b_blk0 + t * TILE_B + wr * 16 + lr;
        float* orow = out + ((size_t)gb * M_TOT + m) * OUT_DIM + wc * 64 + quad * 4;
        #pragma unroll
        for (int j = 0; j < 4; ++j) {
            v4f v = acc[j];
            if (m == 0) {
                const v4f bv = *(const v4f*)&bias[wc * 64 + j * 16 + quad * 4];
                v += bv;
            }
            *(v4f*)(orow + j * 16) = v;
        }
    }
}

extern "C" void kernel_launch(void* const* d_in, const int* in_sizes, int n_in,
                              void* d_out, int out_size, void* d_ws, size_t ws_size,
                              hipStream_t stream) {
    const float* inp  = (const float*)d_in[0];   // [20000, 49, 128] f32
    const float* wgt  = (const float*)d_in[1];   // [7, 128, 128]   f32
    const float* bias = (const float*)d_in[2];   // [128]           f32
    float* out = (float*)d_out;                  // [20000, 49, 128] f32

    dim3 grid(BX, M_TOT);   // 125 x 49 = 6125 blocks
    dim3 block(256);
    so3_linear_kernel<<<grid, block, 0, stream>>>(inp, wgt, bias, out);
}